// Round 3
// baseline (356.146 us; speedup 1.0000x reference)
//
#include <hip/hip_runtime.h>
#include <stdint.h>

#define NPTS 4096
#define NC 128
#define NB 8
#define CSPLIT 8
#define COLS_PER (NPTS / CSPLIT)  // 512
#define RPB 128                   // rows per block (4 waves x 32 rows)

typedef __bf16 bf16x8 __attribute__((ext_vector_type(8)));
typedef float f32x4 __attribute__((ext_vector_type(4)));
typedef unsigned short u16;
typedef unsigned int u32;

__device__ inline u16 f2bf(float x) {
    u32 u = __float_as_uint(x);
    u32 r = (u + 0x7fffu + ((u >> 16) & 1u)) >> 16;
    return (u16)r;
}

// Kernel 1: normalize (blocks 0..63) + per-cloud label histogram (block 64).
// Normalize: float2 global loads (512 B/wave-inst), LDS transpose, bf16 pack.
__global__ __launch_bounds__(256) void norm_count_kernel(const float* __restrict__ feat,
                                                         const int* __restrict__ labels,
                                                         u16* __restrict__ vbf,
                                                         int* __restrict__ counts) {
    int b = blockIdx.y;
    int tid = threadIdx.x;
    if (blockIdx.x == 64) {  // histogram branch
        __shared__ int h[16];
        if (tid < 16) h[tid] = 0;
        __syncthreads();
        for (int n = tid; n < NPTS; n += 256)
            atomicAdd(&h[labels[b * NPTS + n] & 15], 1);
        __syncthreads();
        if (tid < 16) counts[b * 16 + tid] = h[tid];
        return;
    }
    int n0 = blockIdx.x * 64;
    __shared__ float tile[64][129];
    __shared__ float part[8][64];
    __shared__ float rn[64];
    const float* fb = feat + (size_t)b * NC * NPTS;
    int nslot = tid & 31;  // point pair 2*nslot, 2*nslot+1
    int ty = tid >> 5;     // 0..7 c-group
    float s0 = 0.f, s1 = 0.f;
#pragma unroll
    for (int i = 0; i < 16; ++i) {
        int c = i * 8 + ty;
        float2 x = *(const float2*)(fb + (size_t)c * NPTS + n0 + 2 * nslot);
        tile[2 * nslot][c] = x.x;
        tile[2 * nslot + 1][c] = x.y;
        s0 += x.x * x.x;
        s1 += x.y * x.y;
    }
    part[ty][2 * nslot] = s0;
    part[ty][2 * nslot + 1] = s1;
    __syncthreads();
    if (tid < 64) {
        float s = 0.f;
#pragma unroll
        for (int t = 0; t < 8; ++t) s += part[t][tid];
        rn[tid] = 1.f / fmaxf(sqrtf(s), 1e-12f);
    }
    __syncthreads();
    u32* out = (u32*)vbf;
    size_t obase = ((size_t)b * NPTS + n0) * (NC / 2);
#pragma unroll
    for (int i = 0; i < 16; ++i) {
        int idx = tid + i * 256;
        int p = idx >> 6, k = idx & 63;
        float r = rn[p];
        float x0 = tile[p][2 * k] * r;
        float x1 = tile[p][2 * k + 1] * r;
        out[obase + (size_t)p * 64 + k] = (u32)f2bf(x0) | ((u32)f2bf(x1) << 16);
    }
}

// Kernel 2: fused similarity + exp + masked row partial sums.
// 2048 blocks: 32 row-tiles x 8 col-splits x 8 clouds; 128 rows x 512 cols
// each. 32 rows/wave (2 rowsets of 16): each B-frag ds_read feeds 2 MFMAs,
// col staging traffic and barrier count halved vs 16 rows/wave. XOR-swizzled
// LDS (conflict-free, verified 0 in R2). cs = blk&7 -> round-robin dispatch
// pins one 1 MB col-slab per XCD (L2-resident).
__global__ __launch_bounds__(256, 5) void sim_kernel(const u16* __restrict__ vbf,
                                                     const int* __restrict__ labels,
                                                     float2* __restrict__ rowacc) {
    int b = blockIdx.y;
    int cs = blockIdx.x & 7;
    int rt = blockIdx.x >> 3;
    int row0 = rt * RPB;
    int c0 = cs * COLS_PER;
    int tid = threadIdx.x;
    int wave = tid >> 6, lane = tid & 63;
    int quad = lane >> 4, ln = lane & 15;

    const u16* vb = vbf + (size_t)b * NPTS * NC;
    const int* lab = labels + b * NPTS;

    int rbase[2];
    rbase[0] = row0 + wave * 32;
    rbase[1] = rbase[0] + 16;

    bf16x8 afrag[2][4];
#pragma unroll
    for (int s = 0; s < 2; ++s)
#pragma unroll
        for (int f = 0; f < 4; ++f)
            afrag[s][f] = *(const bf16x8*)(vb + (size_t)(rbase[s] + ln) * NC + f * 32 + quad * 8);

    int lrow[2][4];
#pragma unroll
    for (int s = 0; s < 2; ++s)
#pragma unroll
        for (int r = 0; r < 4; ++r) lrow[s][r] = lab[rbase[s] + quad * 4 + r];

    int diagct[2], diagsub[2];
#pragma unroll
    for (int s = 0; s < 2; ++s) {
        diagct[s] = rbase[s] & ~63;
        diagsub[s] = (rbase[s] >> 4) & 3;
    }

    float psame[2][4] = {{0.f}}, sall[2][4] = {{0.f}};

    __shared__ u16 cols[64 * 128];
    __shared__ int clab[64];

    const uint4* src = (const uint4*)(vb + (size_t)c0 * NC);
    int sidx[4];
    u32 woff[4];
#pragma unroll
    for (int i = 0; i < 4; ++i) {
        int idx = tid + i * 256;
        int rr = idx >> 4, cc = idx & 15;
        sidx[i] = idx;
        woff[i] = rr * 128 + ((cc ^ (rr & 15)) * 8);
    }

    for (int t = 0; t < COLS_PER / 64; ++t) {
        int ct = c0 + t * 64;
        __syncthreads();
#pragma unroll
        for (int i = 0; i < 4; ++i)
            *(uint4*)(cols + woff[i]) = src[t * 1024 + sidx[i]];
        if (tid < 64) clab[tid] = lab[ct + tid];
        __syncthreads();

#pragma unroll
        for (int sub = 0; sub < 4; ++sub) {
            const u16* rowb = cols + (sub * 16 + ln) * 128;
            bf16x8 bfrag[4];
#pragma unroll
            for (int f = 0; f < 4; ++f)
                bfrag[f] = *(const bf16x8*)(rowb + (((4 * f + quad) ^ ln) * 8));
            int lc = clab[sub * 16 + ln];
#pragma unroll
            for (int s = 0; s < 2; ++s) {
                f32x4 d = {0.f, 0.f, 0.f, 0.f};
#pragma unroll
                for (int f = 0; f < 4; ++f)
                    d = __builtin_amdgcn_mfma_f32_16x16x32_bf16(afrag[s][f], bfrag[f], d, 0, 0, 0);
                if (ct == diagct[s] && sub == diagsub[s]) {  // wave-uniform, rare
#pragma unroll
                    for (int r = 0; r < 4; ++r) {
                        float e = __expf(d[r]);
                        if (ln == quad * 4 + r) e = 0.f;  // zero the diagonal
                        sall[s][r] += e;
                        psame[s][r] += (lc == lrow[s][r]) ? e : 0.f;
                    }
                } else {
#pragma unroll
                    for (int r = 0; r < 4; ++r) {
                        float e = __expf(d[r]);
                        sall[s][r] += e;
                        psame[s][r] += (lc == lrow[s][r]) ? e : 0.f;
                    }
                }
            }
        }
    }

#pragma unroll
    for (int off = 1; off < 16; off <<= 1)
#pragma unroll
        for (int s = 0; s < 2; ++s)
#pragma unroll
            for (int r = 0; r < 4; ++r) {
                psame[s][r] += __shfl_xor(psame[s][r], off);
                sall[s][r] += __shfl_xor(sall[s][r], off);
            }
    if (ln == 0) {
#pragma unroll
        for (int s = 0; s < 2; ++s)
#pragma unroll
            for (int r = 0; r < 4; ++r)
                rowacc[((size_t)cs * NB + b) * NPTS + rbase[s] + quad * 4 + r] =
                    make_float2(psame[s][r], sall[s][r]);
    }
}

// Kernel 3: per-row finalize + mean; last block (ticket) writes d_out.
__global__ __launch_bounds__(256) void loss_kernel(const float2* __restrict__ rowacc,
                                                   const int* __restrict__ labels,
                                                   const int* __restrict__ counts,
                                                   float* __restrict__ acc,
                                                   u32* __restrict__ ticket,
                                                   float* __restrict__ out) {
    int idx = blockIdx.x * 256 + threadIdx.x;  // 0..B*NPTS-1
    int b = idx >> 12;
    float ps = 0.f, sa = 0.f;
#pragma unroll
    for (int cs = 0; cs < CSPLIT; ++cs) {
        float2 v = rowacc[(size_t)cs * NB * NPTS + idx];
        ps += v.x;
        sa += v.y;
    }
    int lb = labels[idx] & 15;
    int cnt = counts[b * 16 + lb];
    float p = ps / (float)cnt;
    float n = (sa - ps) / (float)(NPTS - cnt);
    float loss = -__logf(p / (p + n));
#pragma unroll
    for (int off = 1; off < 64; off <<= 1) loss += __shfl_xor(loss, off);
    __shared__ float w[4];
    if ((threadIdx.x & 63) == 0) w[threadIdx.x >> 6] = loss;
    __syncthreads();
    if (threadIdx.x == 0) {
        atomicAdd(acc, w[0] + w[1] + w[2] + w[3]);
        __threadfence();
        u32 t = atomicAdd(ticket, 1u);
        if (t == gridDim.x - 1) {  // all blocks' adds visible (fence + ticket)
            float v = atomicAdd(acc, 0.f);  // coherent read of final sum
            out[0] = v * (1.f / (float)(NB * NPTS));
        }
    }
}

extern "C" void kernel_launch(void* const* d_in, const int* in_sizes, int n_in,
                              void* d_out, int out_size, void* d_ws, size_t ws_size,
                              hipStream_t stream) {
    const float* feat = (const float*)d_in[0];
    const int* labels = (const int*)d_in[1];
    float* out = (float*)d_out;

    float* acc = (float*)d_ws;                         // 4 B
    u32* ticket = (u32*)((char*)d_ws + 4);             // 4 B
    int* counts = (int*)((char*)d_ws + 256);           // 64 B
    float2* rowacc = (float2*)((char*)d_ws + 4096);    // 8*8*4096*8 B = 2 MB
    u16* vbf = (u16*)((char*)d_ws + 4096 + (size_t)CSPLIT * NB * NPTS * 8);  // 8 MB

    hipMemsetAsync(d_ws, 0, 8, stream);  // acc + ticket
    norm_count_kernel<<<dim3(65, NB), 256, 0, stream>>>(feat, labels, vbf, counts);
    sim_kernel<<<dim3((NPTS / RPB) * CSPLIT, NB), 256, 0, stream>>>(vbf, labels, rowacc);
    loss_kernel<<<dim3(NB * NPTS / 256), 256, 0, stream>>>(rowacc, labels, counts, acc, ticket, out);
}

// Round 5
// 217.461 us; speedup vs baseline: 1.6377x; 1.6377x over previous
//
#include <hip/hip_runtime.h>
#include <stdint.h>

#define NPTS 4096
#define NC 128
#define NB 8
#define CSPLIT 4
#define COLS_PER (NPTS / CSPLIT)  // 1024
#define RPB 128                   // rows per block (4 waves x 32 rows)

typedef __bf16 bf16x8 __attribute__((ext_vector_type(8)));
typedef float f32x4 __attribute__((ext_vector_type(4)));
typedef unsigned short u16;
typedef unsigned int u32;

__device__ inline u16 f2bf(float x) {
    u32 u = __float_as_uint(x);
    u32 r = (u + 0x7fffu + ((u >> 16) & 1u)) >> 16;
    return (u16)r;
}

// Kernel 1: normalize (blocks 0..63) + per-cloud label histogram (block 64).
__global__ __launch_bounds__(256) void norm_count_kernel(const float* __restrict__ feat,
                                                         const int* __restrict__ labels,
                                                         u16* __restrict__ vbf,
                                                         int* __restrict__ counts) {
    int b = blockIdx.y;
    int tid = threadIdx.x;
    if (blockIdx.x == 64) {  // histogram branch
        __shared__ int h[16];
        if (tid < 16) h[tid] = 0;
        __syncthreads();
        for (int n = tid; n < NPTS; n += 256)
            atomicAdd(&h[labels[b * NPTS + n] & 15], 1);
        __syncthreads();
        if (tid < 16) counts[b * 16 + tid] = h[tid];
        return;
    }
    int n0 = blockIdx.x * 64;
    __shared__ float tile[64][129];
    __shared__ float part[8][64];
    __shared__ float rn[64];
    const float* fb = feat + (size_t)b * NC * NPTS;
    int nslot = tid & 31;  // point pair 2*nslot, 2*nslot+1
    int ty = tid >> 5;     // 0..7 c-group
    float s0 = 0.f, s1 = 0.f;
#pragma unroll
    for (int i = 0; i < 16; ++i) {
        int c = i * 8 + ty;
        float2 x = *(const float2*)(fb + (size_t)c * NPTS + n0 + 2 * nslot);
        tile[2 * nslot][c] = x.x;
        tile[2 * nslot + 1][c] = x.y;
        s0 += x.x * x.x;
        s1 += x.y * x.y;
    }
    part[ty][2 * nslot] = s0;
    part[ty][2 * nslot + 1] = s1;
    __syncthreads();
    if (tid < 64) {
        float s = 0.f;
#pragma unroll
        for (int t = 0; t < 8; ++t) s += part[t][tid];
        rn[tid] = 1.f / fmaxf(sqrtf(s), 1e-12f);
    }
    __syncthreads();
    u32* out = (u32*)vbf;
    size_t obase = ((size_t)b * NPTS + n0) * (NC / 2);
#pragma unroll
    for (int i = 0; i < 16; ++i) {
        int idx = tid + i * 256;
        int p = idx >> 6, k = idx & 63;
        float r = rn[p];
        float x0 = tile[p][2 * k] * r;
        float x1 = tile[p][2 * k + 1] * r;
        out[obase + (size_t)p * 64 + k] = (u32)f2bf(x0) | ((u32)f2bf(x1) << 16);
    }
}

// Kernel 2: similarity + exp + masked row partial sums.
// Grid 1024 = 8 clouds x 32 rowtiles x 4 colsplits = exactly 4 blocks/CU in
// one pass. 128 rows x 1024 cols/block; 32 rows/wave (2 rowsets of 16) so
// each B-frag ds_read_b128 feeds 2 MFMAs. XOR-swizzled LDS (0 conflicts, R2).
// launch_bounds(256,4) -> 128 VGPR cap; NOTE (256,5) spilled catastrophically
// in R3 (48 VGPRs + 362 MB scratch WRITE) -- do not lower the cap below 4.
// Block mapping: combo=bid&31 -> (cloud, cs) so round-robin XCD dispatch
// gives each XCD 4 distinct 1 MB col-slabs = its 4 MB L2.
__global__ __launch_bounds__(256, 4) void sim_kernel(const u16* __restrict__ vbf,
                                                     const int* __restrict__ labels,
                                                     float2* __restrict__ rowacc) {
    int bid = blockIdx.x;
    int rt = bid >> 5;
    int combo = bid & 31;
    int b = combo >> 2;
    int cs = combo & 3;
    int row0 = rt * RPB;
    int c0 = cs * COLS_PER;
    int tid = threadIdx.x;
    int wave = tid >> 6, lane = tid & 63;
    int quad = lane >> 4, ln = lane & 15;

    const u16* vb = vbf + (size_t)b * NPTS * NC;
    const int* lab = labels + b * NPTS;

    int rbase[2];
    rbase[0] = row0 + wave * 32;
    rbase[1] = rbase[0] + 16;

    bf16x8 afrag[2][4];
#pragma unroll
    for (int s = 0; s < 2; ++s)
#pragma unroll
        for (int f = 0; f < 4; ++f)
            afrag[s][f] = *(const bf16x8*)(vb + (size_t)(rbase[s] + ln) * NC + f * 32 + quad * 8);

    int lrow[2][4];
#pragma unroll
    for (int s = 0; s < 2; ++s)
#pragma unroll
        for (int r = 0; r < 4; ++r) lrow[s][r] = lab[rbase[s] + quad * 4 + r];

    int diagct[2], diagsub[2];
#pragma unroll
    for (int s = 0; s < 2; ++s) {
        diagct[s] = rbase[s] & ~63;
        diagsub[s] = (rbase[s] >> 4) & 3;
    }

    float psame[2][4] = {{0.f}}, sall[2][4] = {{0.f}};

    __shared__ u16 cols[64 * 128];
    __shared__ int clab[64];

    const uint4* src = (const uint4*)(vb + (size_t)c0 * NC);
    int sidx[4];
    u32 woff[4];
#pragma unroll
    for (int i = 0; i < 4; ++i) {
        int idx = tid + i * 256;
        int rr = idx >> 4, cc = idx & 15;
        sidx[i] = idx;
        woff[i] = rr * 128 + ((cc ^ (rr & 15)) * 8);
    }

    uint4 pf[4];
#pragma unroll
    for (int i = 0; i < 4; ++i) pf[i] = src[sidx[i]];
    int plab = (tid < 64) ? lab[c0 + tid] : 0;

    for (int t = 0; t < COLS_PER / 64; ++t) {
        int ct = c0 + t * 64;
        __syncthreads();
#pragma unroll
        for (int i = 0; i < 4; ++i) *(uint4*)(cols + woff[i]) = pf[i];
        if (tid < 64) clab[tid] = plab;
        if (t + 1 < COLS_PER / 64) {
#pragma unroll
            for (int i = 0; i < 4; ++i) pf[i] = src[(t + 1) * 1024 + sidx[i]];
            if (tid < 64) plab = lab[ct + 64 + tid];
        }
        __syncthreads();

#pragma unroll
        for (int sub = 0; sub < 4; ++sub) {
            const u16* rowb = cols + (sub * 16 + ln) * 128;
            bf16x8 bfrag[4];
#pragma unroll
            for (int f = 0; f < 4; ++f)
                bfrag[f] = *(const bf16x8*)(rowb + (((4 * f + quad) ^ ln) * 8));
            int lc = clab[sub * 16 + ln];
#pragma unroll
            for (int s = 0; s < 2; ++s) {
                f32x4 d = {0.f, 0.f, 0.f, 0.f};
#pragma unroll
                for (int f = 0; f < 4; ++f)
                    d = __builtin_amdgcn_mfma_f32_16x16x32_bf16(afrag[s][f], bfrag[f], d, 0, 0, 0);
                if (ct == diagct[s] && sub == diagsub[s]) {  // wave-uniform, rare
#pragma unroll
                    for (int r = 0; r < 4; ++r) {
                        float e = __expf(d[r]);
                        if (ln == quad * 4 + r) e = 0.f;  // zero the diagonal
                        sall[s][r] += e;
                        psame[s][r] += (lc == lrow[s][r]) ? e : 0.f;
                    }
                } else {
#pragma unroll
                    for (int r = 0; r < 4; ++r) {
                        float e = __expf(d[r]);
                        sall[s][r] += e;
                        psame[s][r] += (lc == lrow[s][r]) ? e : 0.f;
                    }
                }
            }
        }
    }

#pragma unroll
    for (int off = 1; off < 16; off <<= 1)
#pragma unroll
        for (int s = 0; s < 2; ++s)
#pragma unroll
            for (int r = 0; r < 4; ++r) {
                psame[s][r] += __shfl_xor(psame[s][r], off);
                sall[s][r] += __shfl_xor(sall[s][r], off);
            }
    if (ln == 0) {
#pragma unroll
        for (int s = 0; s < 2; ++s)
#pragma unroll
            for (int r = 0; r < 4; ++r)
                rowacc[((size_t)cs * NB + b) * NPTS + rbase[s] + quad * 4 + r] =
                    make_float2(psame[s][r], sall[s][r]);
    }
}

// Kernel 3: per-row finalize + mean; last block (ticket) writes d_out.
__global__ __launch_bounds__(256) void loss_kernel(const float2* __restrict__ rowacc,
                                                   const int* __restrict__ labels,
                                                   const int* __restrict__ counts,
                                                   float* __restrict__ acc,
                                                   u32* __restrict__ ticket,
                                                   float* __restrict__ out) {
    int idx = blockIdx.x * 256 + threadIdx.x;  // 0..B*NPTS-1
    int b = idx >> 12;
    float ps = 0.f, sa = 0.f;
#pragma unroll
    for (int cs = 0; cs < CSPLIT; ++cs) {
        float2 v = rowacc[(size_t)cs * NB * NPTS + idx];
        ps += v.x;
        sa += v.y;
    }
    int lb = labels[idx] & 15;
    int cnt = counts[b * 16 + lb];
    float p = ps / (float)cnt;
    float n = (sa - ps) / (float)(NPTS - cnt);
    float loss = -__logf(p / (p + n));
#pragma unroll
    for (int off = 1; off < 64; off <<= 1) loss += __shfl_xor(loss, off);
    __shared__ float w[4];
    if ((threadIdx.x & 63) == 0) w[threadIdx.x >> 6] = loss;
    __syncthreads();
    if (threadIdx.x == 0) {
        atomicAdd(acc, w[0] + w[1] + w[2] + w[3]);
        __threadfence();
        u32 t = atomicAdd(ticket, 1u);
        if (t == gridDim.x - 1) {  // all blocks' adds visible (fence + ticket)
            float v = atomicAdd(acc, 0.f);  // coherent read of final sum
            out[0] = v * (1.f / (float)(NB * NPTS));
        }
    }
}

extern "C" void kernel_launch(void* const* d_in, const int* in_sizes, int n_in,
                              void* d_out, int out_size, void* d_ws, size_t ws_size,
                              hipStream_t stream) {
    const float* feat = (const float*)d_in[0];
    const int* labels = (const int*)d_in[1];
    float* out = (float*)d_out;

    float* acc = (float*)d_ws;                       // @0, 4 B
    u32* ticket = (u32*)((char*)d_ws + 4);           // @4, 4 B
    int* counts = (int*)((char*)d_ws + 256);         // @256, 64 B
    float2* rowacc = (float2*)((char*)d_ws + 4096);  // 4*8*4096*8 = 1 MB
    u16* vbf = (u16*)((char*)d_ws + 4096 + (size_t)CSPLIT * NB * NPTS * 8);  // 8 MB

    hipMemsetAsync(d_ws, 0, 768, stream);  // acc + ticket + counts
    norm_count_kernel<<<dim3(65, NB), 256, 0, stream>>>(feat, labels, vbf, counts);
    sim_kernel<<<dim3(32 * 32), 256, 0, stream>>>(vbf, labels, rowacc);
    loss_kernel<<<dim3(NB * NPTS / 256), 256, 0, stream>>>(rowacc, labels, counts, acc, ticket, out);
}

// Round 6
// 133.591 us; speedup vs baseline: 2.6659x; 1.6278x over previous
//
#include <hip/hip_runtime.h>
#include <stdint.h>

#define NPTS 4096
#define NC 128
#define NB 8
#define CSPLIT 4
#define COLS_PER (NPTS / CSPLIT)  // 1024
#define RPB 128                   // rows per block (4 waves x 32 rows)

typedef __bf16 bf16x8 __attribute__((ext_vector_type(8)));
typedef float f32x4 __attribute__((ext_vector_type(4)));
typedef unsigned short u16;
typedef unsigned int u32;

__device__ inline u16 f2bf(float x) {
    u32 u = __float_as_uint(x);
    u32 r = (u + 0x7fffu + ((u >> 16) & 1u)) >> 16;
    return (u16)r;
}

// Kernel 1: normalize (blocks 0..63) + per-cloud label histogram (block 64).
__global__ __launch_bounds__(256) void norm_count_kernel(const float* __restrict__ feat,
                                                         const int* __restrict__ labels,
                                                         u16* __restrict__ vbf,
                                                         int* __restrict__ counts) {
    int b = blockIdx.y;
    int tid = threadIdx.x;
    if (blockIdx.x == 64) {  // histogram branch
        __shared__ int h[16];
        if (tid < 16) h[tid] = 0;
        __syncthreads();
        for (int n = tid; n < NPTS; n += 256)
            atomicAdd(&h[labels[b * NPTS + n] & 15], 1);
        __syncthreads();
        if (tid < 16) counts[b * 16 + tid] = h[tid];
        return;
    }
    int n0 = blockIdx.x * 64;
    __shared__ float tile[64][129];
    __shared__ float part[8][64];
    __shared__ float rn[64];
    const float* fb = feat + (size_t)b * NC * NPTS;
    int nslot = tid & 31;  // point pair 2*nslot, 2*nslot+1
    int ty = tid >> 5;     // 0..7 c-group
    float s0 = 0.f, s1 = 0.f;
#pragma unroll
    for (int i = 0; i < 16; ++i) {
        int c = i * 8 + ty;
        float2 x = *(const float2*)(fb + (size_t)c * NPTS + n0 + 2 * nslot);
        tile[2 * nslot][c] = x.x;
        tile[2 * nslot + 1][c] = x.y;
        s0 += x.x * x.x;
        s1 += x.y * x.y;
    }
    part[ty][2 * nslot] = s0;
    part[ty][2 * nslot + 1] = s1;
    __syncthreads();
    if (tid < 64) {
        float s = 0.f;
#pragma unroll
        for (int t = 0; t < 8; ++t) s += part[t][tid];
        rn[tid] = 1.f / fmaxf(sqrtf(s), 1e-12f);
    }
    __syncthreads();
    u32* out = (u32*)vbf;
    size_t obase = ((size_t)b * NPTS + n0) * (NC / 2);
#pragma unroll
    for (int i = 0; i < 16; ++i) {
        int idx = tid + i * 256;
        int p = idx >> 6, k = idx & 63;
        float r = rn[p];
        float x0 = tile[p][2 * k] * r;
        float x1 = tile[p][2 * k + 1] * r;
        out[obase + (size_t)p * 64 + k] = (u32)f2bf(x0) | ((u32)f2bf(x1) << 16);
    }
}

// Kernel 2: similarity + exp + masked row partial sums.
// Grid 1024 = 8 clouds x 32 rowtiles x 4 colsplits = 4 blocks/CU in one pass.
// 128 rows x 1024 cols/block; 32 rows/wave (2 rowsets of 16) so each B-frag
// ds_read_b128 feeds 2 MFMAs. XOR-swizzled LDS (0 conflicts since R2).
//
// REGISTER BUDGET (hard-won): on gfx950 the 2nd launch_bounds arg caps ARCH
// VGPRs at 256/min_waves, NOT 512/min_waves:
//   (256,8)->32 [R2, ok], (256,5)->48 [R3, 362MB spill], (256,4)->64
//   [R5, 379MB spill]. Hot loop needs ~95 arch VGPRs -> use (256,2) = 128
//   cap. No register prefetch (R2-style direct staging loads): 4 blocks/CU
//   co-scheduling hides the global->LDS latency (m114).
__global__ __launch_bounds__(256, 2) void sim_kernel(const u16* __restrict__ vbf,
                                                     const int* __restrict__ labels,
                                                     float2* __restrict__ rowacc) {
    int bid = blockIdx.x;
    int rt = bid >> 5;
    int combo = bid & 31;  // (cloud, cs): round-robin XCD dispatch gives each
    int b = combo >> 2;    // XCD 4 distinct 1 MB col-slabs = its 4 MB L2
    int cs = combo & 3;
    int row0 = rt * RPB;
    int c0 = cs * COLS_PER;
    int tid = threadIdx.x;
    int wave = tid >> 6, lane = tid & 63;
    int quad = lane >> 4, ln = lane & 15;

    const u16* vb = vbf + (size_t)b * NPTS * NC;
    const int* lab = labels + b * NPTS;

    int rbase[2];
    rbase[0] = row0 + wave * 32;
    rbase[1] = rbase[0] + 16;

    bf16x8 afrag[2][4];
#pragma unroll
    for (int s = 0; s < 2; ++s)
#pragma unroll
        for (int f = 0; f < 4; ++f)
            afrag[s][f] = *(const bf16x8*)(vb + (size_t)(rbase[s] + ln) * NC + f * 32 + quad * 8);

    int lrow[2][4];
#pragma unroll
    for (int s = 0; s < 2; ++s)
#pragma unroll
        for (int r = 0; r < 4; ++r) lrow[s][r] = lab[rbase[s] + quad * 4 + r];

    int diagct[2], diagsub[2];
#pragma unroll
    for (int s = 0; s < 2; ++s) {
        diagct[s] = rbase[s] & ~63;
        diagsub[s] = (rbase[s] >> 4) & 3;
    }

    float psame[2][4] = {{0.f}}, sall[2][4] = {{0.f}};

    __shared__ u16 cols[64 * 128];
    __shared__ int clab[64];

    const uint4* src = (const uint4*)(vb + (size_t)c0 * NC);
    int sidx = tid;  // 4 chunks of 256
    u32 woff[4];
#pragma unroll
    for (int i = 0; i < 4; ++i) {
        int idx = tid + i * 256;
        int rr = idx >> 4, cc = idx & 15;
        woff[i] = rr * 128 + ((cc ^ (rr & 15)) * 8);
    }

    for (int t = 0; t < COLS_PER / 64; ++t) {
        int ct = c0 + t * 64;
        __syncthreads();
#pragma unroll
        for (int i = 0; i < 4; ++i)
            *(uint4*)(cols + woff[i]) = src[t * 1024 + sidx + i * 256];
        if (tid < 64) clab[tid] = lab[ct + tid];
        __syncthreads();

#pragma unroll
        for (int sub = 0; sub < 4; ++sub) {
            const u16* rowb = cols + (sub * 16 + ln) * 128;
            bf16x8 bfrag[4];
#pragma unroll
            for (int f = 0; f < 4; ++f)
                bfrag[f] = *(const bf16x8*)(rowb + (((4 * f + quad) ^ ln) * 8));
            int lc = clab[sub * 16 + ln];
#pragma unroll
            for (int s = 0; s < 2; ++s) {
                f32x4 d = {0.f, 0.f, 0.f, 0.f};
#pragma unroll
                for (int f = 0; f < 4; ++f)
                    d = __builtin_amdgcn_mfma_f32_16x16x32_bf16(afrag[s][f], bfrag[f], d, 0, 0, 0);
                if (ct == diagct[s] && sub == diagsub[s]) {  // wave-uniform, rare
#pragma unroll
                    for (int r = 0; r < 4; ++r) {
                        float e = __expf(d[r]);
                        if (ln == quad * 4 + r) e = 0.f;  // zero the diagonal
                        sall[s][r] += e;
                        psame[s][r] += (lc == lrow[s][r]) ? e : 0.f;
                    }
                } else {
#pragma unroll
                    for (int r = 0; r < 4; ++r) {
                        float e = __expf(d[r]);
                        sall[s][r] += e;
                        psame[s][r] += (lc == lrow[s][r]) ? e : 0.f;
                    }
                }
            }
        }
    }

#pragma unroll
    for (int off = 1; off < 16; off <<= 1)
#pragma unroll
        for (int s = 0; s < 2; ++s)
#pragma unroll
            for (int r = 0; r < 4; ++r) {
                psame[s][r] += __shfl_xor(psame[s][r], off);
                sall[s][r] += __shfl_xor(sall[s][r], off);
            }
    if (ln == 0) {
#pragma unroll
        for (int s = 0; s < 2; ++s)
#pragma unroll
            for (int r = 0; r < 4; ++r)
                rowacc[((size_t)cs * NB + b) * NPTS + rbase[s] + quad * 4 + r] =
                    make_float2(psame[s][r], sall[s][r]);
    }
}

// Kernel 3: per-row finalize + mean; last block (ticket) writes d_out.
__global__ __launch_bounds__(256) void loss_kernel(const float2* __restrict__ rowacc,
                                                   const int* __restrict__ labels,
                                                   const int* __restrict__ counts,
                                                   float* __restrict__ acc,
                                                   u32* __restrict__ ticket,
                                                   float* __restrict__ out) {
    int idx = blockIdx.x * 256 + threadIdx.x;  // 0..B*NPTS-1
    int b = idx >> 12;
    float ps = 0.f, sa = 0.f;
#pragma unroll
    for (int cs = 0; cs < CSPLIT; ++cs) {
        float2 v = rowacc[(size_t)cs * NB * NPTS + idx];
        ps += v.x;
        sa += v.y;
    }
    int lb = labels[idx] & 15;
    int cnt = counts[b * 16 + lb];
    float p = ps / (float)cnt;
    float n = (sa - ps) / (float)(NPTS - cnt);
    float loss = -__logf(p / (p + n));
#pragma unroll
    for (int off = 1; off < 64; off <<= 1) loss += __shfl_xor(loss, off);
    __shared__ float w[4];
    if ((threadIdx.x & 63) == 0) w[threadIdx.x >> 6] = loss;
    __syncthreads();
    if (threadIdx.x == 0) {
        atomicAdd(acc, w[0] + w[1] + w[2] + w[3]);
        __threadfence();
        u32 t = atomicAdd(ticket, 1u);
        if (t == gridDim.x - 1) {  // all blocks' adds visible (fence + ticket)
            float v = atomicAdd(acc, 0.f);  // coherent read of final sum
            out[0] = v * (1.f / (float)(NB * NPTS));
        }
    }
}

extern "C" void kernel_launch(void* const* d_in, const int* in_sizes, int n_in,
                              void* d_out, int out_size, void* d_ws, size_t ws_size,
                              hipStream_t stream) {
    const float* feat = (const float*)d_in[0];
    const int* labels = (const int*)d_in[1];
    float* out = (float*)d_out;

    float* acc = (float*)d_ws;                       // @0, 4 B
    u32* ticket = (u32*)((char*)d_ws + 4);           // @4, 4 B
    int* counts = (int*)((char*)d_ws + 256);         // @256, 64 B
    float2* rowacc = (float2*)((char*)d_ws + 4096);  // 4*8*4096*8 = 1 MB
    u16* vbf = (u16*)((char*)d_ws + 4096 + (size_t)CSPLIT * NB * NPTS * 8);  // 8 MB

    hipMemsetAsync(d_ws, 0, 768, stream);  // acc + ticket + counts
    norm_count_kernel<<<dim3(65, NB), 256, 0, stream>>>(feat, labels, vbf, counts);
    sim_kernel<<<dim3(32 * 32), 256, 0, stream>>>(vbf, labels, rowacc);
    loss_kernel<<<dim3(NB * NPTS / 256), 256, 0, stream>>>(rowacc, labels, counts, acc, ticket, out);
}